// Round 6
// baseline (152.260 us; speedup 1.0000x reference)
//
#include <hip/hip_runtime.h>
#include <math.h>

#define BDIM 256

// Anchors per layer: l0 = mask[6,7,8], l1 = [3,4,5], l2 = [0,1,2]
__device__ __constant__ float c_aw[3][3] = {{116.f,156.f,373.f},{30.f,62.f,59.f},{10.f,16.f,33.f}};
__device__ __constant__ float c_ah[3][3] = {{90.f,198.f,326.f},{61.f,45.f,119.f},{13.f,30.f,23.f}};

// acc[l*8+q]: q0 S_all(bce all 85 ch), q1 sub(bce ch0..4), q2 xy, q3 wh,
//             q4 conf, q5 obj, q6 s1(obj*bls), q7 ni((1-obj)*ignore)
// ws: acc @0 (24 dbl, 192B) | cnt @192 (24 int, 96B) | done @288 (1 int) |
//     tbox @512 (85176 f4) | pbox @1363328 (85176 f4) | noobj @2726144 (85176 f)
// Global cell bases per layer: {0, 4056, 20280}.

// Fast bce: v_exp(-|x|) is 1 inst (input mods) + v_add + v_log + 4 cheap ops.
// Used for ALL bce sums; S_all - sub cancellation is exact (same fn both paths).
__device__ __forceinline__ float bce_fast(float z, float x) {
    float t = __expf(-fabsf(x));
    return fmaxf(x, 0.f) - x * z + __logf(1.f + t);
}
__device__ __forceinline__ float bce4(const float4& z, const float4& x) {
    return bce_fast(z.x, x.x) + bce_fast(z.y, x.y)
         + bce_fast(z.z, x.z) + bce_fast(z.w, x.w);
}

// ---- Kernel A: streaming S_all (blocks 0..1763) + per-cell pass (1764..2097)
__global__ __launch_bounds__(BDIM) void mega_a(
    const float* __restrict__ o0, const float* __restrict__ l0,
    const float* __restrict__ o1, const float* __restrict__ l1,
    const float* __restrict__ o2, const float* __restrict__ l2,
    double* __restrict__ acc, int* __restrict__ cnt, float4* __restrict__ tbox,
    float4* __restrict__ pbox, float* __restrict__ noobj)
{
    if (blockIdx.x < 1764) {
        // streaming role: 32 B/thread/tensor per iter (2 adjacent float4 each)
        int layer, blk0, nblk, n8;
        const float4 *O4, *L4;
        if (blockIdx.x < 84)       { layer=0; blk0=0;   nblk=84;   n8=43095;  O4=(const float4*)o0; L4=(const float4*)l0; }
        else if (blockIdx.x < 420) { layer=1; blk0=84;  nblk=336;  n8=172380; O4=(const float4*)o1; L4=(const float4*)l1; }
        else                       { layer=2; blk0=420; nblk=1344; n8=689520; O4=(const float4*)o2; L4=(const float4*)l2; }

        float s0 = 0.f, s1 = 0.f;
        for (int i = (int)(blockIdx.x - blk0) * BDIM + (int)threadIdx.x; i < n8;
             i += nblk * BDIM) {
            float4 a0 = O4[2*i], a1 = O4[2*i+1];
            float4 b0 = L4[2*i], b1 = L4[2*i+1];
            s0 += bce4(b0, a0);
            s1 += bce4(b1, a1);
        }
        float s = s0 + s1;
        __shared__ float sb[4];
        #pragma unroll
        for (int off = 32; off > 0; off >>= 1) s += __shfl_down(s, off, 64);
        if ((threadIdx.x & 63) == 0) sb[threadIdx.x >> 6] = s;
        __syncthreads();
        if (threadIdx.x == 0) {
            double t = (double)sb[0] + (double)sb[1] + (double)sb[2] + (double)sb[3];
            atomicAdd(&acc[layer * 8 + 0], t);
        }
        return;
    }

    // cell role: channels 0..4, box decode, target compaction
    int cb = blockIdx.x - 1764;           // 0..333
    int layer, blk0;
    if (cb < 16)      { layer = 0; blk0 = 0; }
    else if (cb < 80) { layer = 1; blk0 = 16; }
    else              { layer = 2; blk0 = 80; }
    const int g     = (layer == 0) ? 13 : (layer == 1) ? 26 : 52;
    const int Nlimg = g * g * 3;
    const int Cl    = 8 * Nlimg;
    const int cbase = (layer == 0) ? 0 : (layer == 1) ? 4056 : 20280;
    const float* O  = (layer == 0) ? o0 : (layer == 1) ? o1 : o2;
    const float* L  = (layer == 0) ? l0 : (layer == 1) ? l1 : l2;
    const float gf  = (float)g;
    const float inp = gf * 32.f;

    int cell = (cb - blk0) * BDIM + (int)threadIdx.x;
    float s_sub=0.f, s_xy=0.f, s_wh=0.f, s_conf=0.f, s_obj=0.f, s_s1=0.f;
    if (cell < Cl) {
        const float* op = O + (size_t)cell * 85;
        const float* lp = L + (size_t)cell * 85;
        float x0=op[0], x1=op[1], x2=op[2], x3=op[3], x4=op[4];
        float lx=lp[0], ly=lp[1], lw=lp[2], lh=lp[3], lobj=lp[4];
        int a  = cell % 3;
        int xi = (cell / 3) % g;
        int yi = (cell / (3 * g)) % g;
        int b  = cell / Nlimg;
        float aw = c_aw[layer][a], ah = c_ah[layer][a];

        float c4 = bce_fast(lobj, x4);
        s_sub  = bce_fast(lx,x0) + bce_fast(ly,x1)
               + bce_fast(lw,x2) + bce_fast(lh,x3) + c4;
        s_conf = c4;
        s_obj  = lobj;
        s_xy   = bce_fast(lx*gf - (float)xi, x0) + bce_fast(ly*gf - (float)yi, x1);

        // accurate exp/sigmoid here: pbox feeds a 0.5-threshold compare
        float px = (1.f/(1.f+expf(-x0)) + (float)xi) / gf;
        float py = (1.f/(1.f+expf(-x1)) + (float)yi) / gf;
        float pw = expf(x2) * aw / inp;
        float ph = expf(x3) * ah / inp;
        pbox[cbase + cell]  = make_float4(px, py, pw, ph);
        noobj[cbase + cell] = 1.f - lobj;

        if (lobj != 0.f) {
            float bls = 2.f - lw * lh;
            s_s1 = lobj * bls;
            float dw = logf(lw * inp / aw) - x2;   // accurate log: wh is a raw sum
            float dh = logf(lh * inp / ah) - x3;
            s_wh = lobj * bls * 0.5f * (dw * dw + dh * dh);
            int idx = atomicAdd(&cnt[layer * 8 + b], 1);
            tbox[cbase + b * Nlimg + idx] = make_float4(lx, ly, lw, lh);
        }
    }

    __shared__ float sb6[6][4];
    float v[6] = {s_sub, s_xy, s_wh, s_conf, s_obj, s_s1};
    #pragma unroll
    for (int q = 0; q < 6; q++) {
        float x = v[q];
        #pragma unroll
        for (int off = 32; off > 0; off >>= 1) x += __shfl_down(x, off, 64);
        if ((threadIdx.x & 63) == 0) sb6[q][threadIdx.x >> 6] = x;
    }
    __syncthreads();
    if (threadIdx.x < 6) {
        int q = threadIdx.x;
        double t = (double)sb6[q][0] + (double)sb6[q][1]
                 + (double)sb6[q][2] + (double)sb6[q][3];
        atomicAdd(&acc[layer * 8 + 1 + q], t);
    }
}

// ---- Kernel B: ignore-mask + fused last-block finalize ----------------------
// Wave-uniform tbox[j] reads -> cache broadcast; no LDS staging needed.
#define NB_IGNORE 336
__global__ __launch_bounds__(BDIM) void ignore_fin(
    double* __restrict__ acc, const int* __restrict__ cnt,
    const float4* __restrict__ tbox, const float4* __restrict__ pbox,
    const float* __restrict__ noobj, int* __restrict__ done,
    float* __restrict__ out)
{
    int layer, img, chunk;
    if (blockIdx.x < 16)      { layer = 0; img = blockIdx.x >> 1; chunk = blockIdx.x & 1; }
    else if (blockIdx.x < 80) { int t = blockIdx.x - 16; layer = 1; img = t >> 3; chunk = t & 7; }
    else                      { int t = blockIdx.x - 80; layer = 2; img = t >> 5; chunk = t & 31; }
    const int g     = (layer == 0) ? 13 : (layer == 1) ? 26 : 52;
    const int Nlimg = g * g * 3;
    const int cbase = (layer == 0) ? 0 : (layer == 1) ? 4056 : 20280;

    int ci = chunk * BDIM + (int)threadIdx.x;
    bool live = (ci < Nlimg);
    int cell = cbase + img * Nlimg + (live ? ci : 0);

    float pminx=0, pmaxx=0, pminy=0, pmaxy=0, a1=0, nb=0;
    if (live) {
        float4 p = pbox[cell];
        pminx = p.x - p.z*0.5f; pmaxx = p.x + p.z*0.5f;
        pminy = p.y - p.w*0.5f; pmaxy = p.y + p.w*0.5f;
        a1 = p.z * p.w;
        nb = noobj[cell];
    }
    int n = cnt[layer * 8 + img];
    const float4* tp = tbox + cbase + img * Nlimg;

    // best starts at -1 (replicates where(valid, iou, -1)); dead lanes start
    // "decided" so they don't block the wave-level early exit.
    float best = live ? -1.f : 1e9f;
    for (int j = 0; j < n; j++) {
        if (__all(best >= 0.5f)) break;     // whole wave decided
        float4 t = tp[j];                   // wave-uniform address -> broadcast
        float hw = t.z*0.5f, hh = t.w*0.5f;
        // reference uses maximum for BOTH mins and maxes (replicated bug)
        float imnx = fmaxf(pminx, t.x - hw);
        float imxx = fmaxf(pmaxx, t.x + hw);
        float imny = fmaxf(pminy, t.y - hh);
        float imxy = fmaxf(pmaxy, t.y + hh);
        float iw = fmaxf(imxx - imnx, 0.f);
        float ih = fmaxf(imxy - imny, 0.f);
        float inter = iw * ih;
        float iou = inter / (a1 + t.z*t.w - inter);
        best = fmaxf(best, iou);
    }
    float v = (live && best < 0.5f) ? nb : 0.f;

    __shared__ float sb[4];
    #pragma unroll
    for (int off = 32; off > 0; off >>= 1) v += __shfl_down(v, off, 64);
    if ((threadIdx.x & 63) == 0) sb[threadIdx.x >> 6] = v;
    __syncthreads();
    if (threadIdx.x == 0) {
        double t = (double)sb[0] + (double)sb[1] + (double)sb[2] + (double)sb[3];
        atomicAdd(&acc[layer * 8 + 7], t);           // device-scope
        __threadfence();
        int old = atomicAdd(done, 1);
        if (old == NB_IGNORE - 1) {
            // last block: all acc[·] contributions are fenced + visible
            __threadfence();
            double loss = 0.0;
            const int gs[3] = {13, 26, 52};
            for (int l = 0; l < 3; l++) {
                double C = 8.0 * gs[l] * gs[l] * 3.0;
                double q[8];
                #pragma unroll
                for (int k = 0; k < 8; k++)
                    q[k] = __hip_atomic_load(&acc[l*8+k], __ATOMIC_RELAXED,
                                             __HIP_MEMORY_SCOPE_AGENT);
                double cls = (q[0] - q[1]) / (C * 80.0);
                loss += ( (q[2]/(C*2.0))*q[6] + q[3]
                        + (q[4]/C)*(q[5]+q[7]) + cls*q[5] ) / 8.0;
            }
            out[0] = (float)loss;
        }
    }
}

extern "C" void kernel_launch(void* const* d_in, const int* in_sizes, int n_in,
                              void* d_out, int out_size, void* d_ws, size_t ws_size,
                              hipStream_t stream)
{
    const float* o0 = (const float*)d_in[0];
    const float* l0 = (const float*)d_in[1];
    const float* o1 = (const float*)d_in[2];
    const float* l1 = (const float*)d_in[3];
    const float* o2 = (const float*)d_in[4];
    const float* l2 = (const float*)d_in[5];

    double* acc   = (double*)d_ws;
    int*    cnt   = (int*)((char*)d_ws + 192);
    int*    done  = (int*)((char*)d_ws + 288);
    float4* tbox  = (float4*)((char*)d_ws + 512);
    float4* pbox  = (float4*)((char*)d_ws + 1363328);
    float*  noobj = (float*)((char*)d_ws + 2726144);

    hipMemsetAsync(d_ws, 0, 512, stream);   // zero acc + cnt + done
    mega_a<<<2098, BDIM, 0, stream>>>(o0, l0, o1, l1, o2, l2,
                                      acc, cnt, tbox, pbox, noobj);
    ignore_fin<<<NB_IGNORE, BDIM, 0, stream>>>(acc, cnt, tbox, pbox, noobj,
                                               done, (float*)d_out);
}

// Round 7
// 147.143 us; speedup vs baseline: 1.0348x; 1.0348x over previous
//
#include <hip/hip_runtime.h>
#include <math.h>

#define BDIM 256

// Anchors per layer: l0 = mask[6,7,8], l1 = [3,4,5], l2 = [0,1,2]
__device__ __constant__ float c_aw[3][3] = {{116.f,156.f,373.f},{30.f,62.f,59.f},{10.f,16.f,33.f}};
__device__ __constant__ float c_ah[3][3] = {{90.f,198.f,326.f},{61.f,45.f,119.f},{13.f,30.f,23.f}};

// acc[l*8+q]: q0 S_all(bce all 85 ch), q1 sub(bce ch0..4), q2 xy, q3 wh,
//             q4 conf, q5 obj, q6 s1(obj*bls), q7 ni((1-obj)*ignore)
// ws: acc @0 (24 dbl, 192B) | cnt @192 (24 int, 96B) | done @288 (1 int) |
//     tbox @512 (85176 f4) | pbox @1363328 (85176 f4) | noobj @2726144 (85176 f)
// Global cell bases per layer: {0, 4056, 20280}.

// Fast bce: v_exp(-|x|) + v_add + v_log + 4 cheap ops. Used for ALL bce sums;
// the S_all - sub cancellation is exact (same fn both paths).
__device__ __forceinline__ float bce_fast(float z, float x) {
    float t = __expf(-fabsf(x));
    return fmaxf(x, 0.f) - x * z + __logf(1.f + t);
}
__device__ __forceinline__ float bce4(const float4& z, const float4& x) {
    return bce_fast(z.x, x.x) + bce_fast(z.y, x.y)
         + bce_fast(z.z, x.z) + bce_fast(z.w, x.w);
}

// ---- Kernel A: streaming S_all (blocks 0..1763) + per-cell pass (1764..2097)
__global__ __launch_bounds__(BDIM) void mega_a(
    const float* __restrict__ o0, const float* __restrict__ l0,
    const float* __restrict__ o1, const float* __restrict__ l1,
    const float* __restrict__ o2, const float* __restrict__ l2,
    double* __restrict__ acc, int* __restrict__ cnt, float4* __restrict__ tbox,
    float4* __restrict__ pbox, float* __restrict__ noobj)
{
    if (blockIdx.x < 1764) {
        // streaming role: 32 B/thread/tensor per iter (2 adjacent float4 each);
        // wave covers a contiguous 2 KB segment per array per iteration.
        int layer, blk0, nblk, n8;
        const float4 *O4, *L4;
        if (blockIdx.x < 84)       { layer=0; blk0=0;   nblk=84;   n8=43095;  O4=(const float4*)o0; L4=(const float4*)l0; }
        else if (blockIdx.x < 420) { layer=1; blk0=84;  nblk=336;  n8=172380; O4=(const float4*)o1; L4=(const float4*)l1; }
        else                       { layer=2; blk0=420; nblk=1344; n8=689520; O4=(const float4*)o2; L4=(const float4*)l2; }

        float s0 = 0.f, s1 = 0.f;
        for (int i = (int)(blockIdx.x - blk0) * BDIM + (int)threadIdx.x; i < n8;
             i += nblk * BDIM) {
            float4 a0 = O4[2*i], a1 = O4[2*i+1];
            float4 b0 = L4[2*i], b1 = L4[2*i+1];
            s0 += bce4(b0, a0);
            s1 += bce4(b1, a1);
        }
        float s = s0 + s1;
        __shared__ float sb[4];
        #pragma unroll
        for (int off = 32; off > 0; off >>= 1) s += __shfl_down(s, off, 64);
        if ((threadIdx.x & 63) == 0) sb[threadIdx.x >> 6] = s;
        __syncthreads();
        if (threadIdx.x == 0) {
            double t = (double)sb[0] + (double)sb[1] + (double)sb[2] + (double)sb[3];
            atomicAdd(&acc[layer * 8 + 0], t);
        }
        return;
    }

    // cell role: channels 0..4, box decode, target compaction
    int cb = blockIdx.x - 1764;           // 0..333
    int layer, blk0;
    if (cb < 16)      { layer = 0; blk0 = 0; }
    else if (cb < 80) { layer = 1; blk0 = 16; }
    else              { layer = 2; blk0 = 80; }
    const int g     = (layer == 0) ? 13 : (layer == 1) ? 26 : 52;
    const int Nlimg = g * g * 3;
    const int Cl    = 8 * Nlimg;
    const int cbase = (layer == 0) ? 0 : (layer == 1) ? 4056 : 20280;
    const float* O  = (layer == 0) ? o0 : (layer == 1) ? o1 : o2;
    const float* L  = (layer == 0) ? l0 : (layer == 1) ? l1 : l2;
    const float gf  = (float)g;
    const float inp = gf * 32.f;

    int cell = (cb - blk0) * BDIM + (int)threadIdx.x;
    float s_sub=0.f, s_xy=0.f, s_wh=0.f, s_conf=0.f, s_obj=0.f, s_s1=0.f;
    if (cell < Cl) {
        const float* op = O + (size_t)cell * 85;
        const float* lp = L + (size_t)cell * 85;
        float x0=op[0], x1=op[1], x2=op[2], x3=op[3], x4=op[4];
        float lx=lp[0], ly=lp[1], lw=lp[2], lh=lp[3], lobj=lp[4];
        int a  = cell % 3;
        int xi = (cell / 3) % g;
        int yi = (cell / (3 * g)) % g;
        int b  = cell / Nlimg;
        float aw = c_aw[layer][a], ah = c_ah[layer][a];

        float c4 = bce_fast(lobj, x4);
        s_sub  = bce_fast(lx,x0) + bce_fast(ly,x1)
               + bce_fast(lw,x2) + bce_fast(lh,x3) + c4;
        s_conf = c4;
        s_obj  = lobj;
        s_xy   = bce_fast(lx*gf - (float)xi, x0) + bce_fast(ly*gf - (float)yi, x1);

        // accurate exp/sigmoid here: pbox feeds a 0.5-threshold compare
        float px = (1.f/(1.f+expf(-x0)) + (float)xi) / gf;
        float py = (1.f/(1.f+expf(-x1)) + (float)yi) / gf;
        float pw = expf(x2) * aw / inp;
        float ph = expf(x3) * ah / inp;
        pbox[cbase + cell]  = make_float4(px, py, pw, ph);
        noobj[cbase + cell] = 1.f - lobj;

        if (lobj != 0.f) {
            float bls = 2.f - lw * lh;
            s_s1 = lobj * bls;
            float dw = logf(lw * inp / aw) - x2;   // accurate log: wh is a raw sum
            float dh = logf(lh * inp / ah) - x3;
            s_wh = lobj * bls * 0.5f * (dw * dw + dh * dh);
            int idx = atomicAdd(&cnt[layer * 8 + b], 1);
            tbox[cbase + b * Nlimg + idx] = make_float4(lx, ly, lw, lh);
        }
    }

    __shared__ float sb6[6][4];
    float v[6] = {s_sub, s_xy, s_wh, s_conf, s_obj, s_s1};
    #pragma unroll
    for (int q = 0; q < 6; q++) {
        float x = v[q];
        #pragma unroll
        for (int off = 32; off > 0; off >>= 1) x += __shfl_down(x, off, 64);
        if ((threadIdx.x & 63) == 0) sb6[q][threadIdx.x >> 6] = x;
    }
    __syncthreads();
    if (threadIdx.x < 6) {
        int q = threadIdx.x;
        double t = (double)sb6[q][0] + (double)sb6[q][1]
                 + (double)sb6[q][2] + (double)sb6[q][3];
        atomicAdd(&acc[layer * 8 + 1 + q], t);
    }
}

// ---- Kernel B: ignore-mask (LDS-staged targets) + fused last-block finalize -
// LDS staging keeps the inner IoU loop pure-register (pipelined bulk loads);
// the R6 wave-uniform-load + ballot variant serialized on load latency.
#define TCAP 512
#define NB_IGNORE 336
__global__ __launch_bounds__(BDIM) void ignore_fin(
    double* __restrict__ acc, const int* __restrict__ cnt,
    const float4* __restrict__ tbox, const float4* __restrict__ pbox,
    const float* __restrict__ noobj, int* __restrict__ done,
    float* __restrict__ out)
{
    int layer, img, chunk;
    if (blockIdx.x < 16)      { layer = 0; img = blockIdx.x >> 1; chunk = blockIdx.x & 1; }
    else if (blockIdx.x < 80) { int t = blockIdx.x - 16; layer = 1; img = t >> 3; chunk = t & 7; }
    else                      { int t = blockIdx.x - 80; layer = 2; img = t >> 5; chunk = t & 31; }
    const int g     = (layer == 0) ? 13 : (layer == 1) ? 26 : 52;
    const int Nlimg = g * g * 3;
    const int cbase = (layer == 0) ? 0 : (layer == 1) ? 4056 : 20280;

    int ci = chunk * BDIM + (int)threadIdx.x;
    bool live = (ci < Nlimg);
    int cell = cbase + img * Nlimg + (live ? ci : 0);

    float pminx=0, pmaxx=0, pminy=0, pmaxy=0, a1=0, nb=0;
    if (live) {
        float4 p = pbox[cell];
        pminx = p.x - p.z*0.5f; pmaxx = p.x + p.z*0.5f;
        pminy = p.y - p.w*0.5f; pmaxy = p.y + p.w*0.5f;
        a1 = p.z * p.w;
        nb = noobj[cell];
    }
    int n = cnt[layer * 8 + img];
    const float4* tp = tbox + cbase + img * Nlimg;

    __shared__ float4 sT[TCAP];
    float best = -1.f;                 // replicates where(valid, iou, -1)
    bool donef = !live;
    for (int t0 = 0; t0 < n; t0 += TCAP) {
        int tn = min(TCAP, n - t0);
        __syncthreads();
        for (int i = threadIdx.x; i < tn; i += BDIM) sT[i] = tp[t0 + i];
        __syncthreads();
        if (!donef) {
            for (int j = 0; j < tn; j++) {
                float4 t = sT[j];
                float hw = t.z*0.5f, hh = t.w*0.5f;
                // reference uses maximum for BOTH mins and maxes (replicated bug)
                float imnx = fmaxf(pminx, t.x - hw);
                float imxx = fmaxf(pmaxx, t.x + hw);
                float imny = fmaxf(pminy, t.y - hh);
                float imxy = fmaxf(pmaxy, t.y + hh);
                float iw = fmaxf(imxx - imnx, 0.f);
                float ih = fmaxf(imxy - imny, 0.f);
                float inter = iw * ih;
                float iou = inter / (a1 + t.z*t.w - inter);
                best = fmaxf(best, iou);
                if (best >= 0.5f) { donef = true; break; }
            }
        }
    }
    float v = (live && best < 0.5f) ? nb : 0.f;

    __shared__ float sb[4];
    #pragma unroll
    for (int off = 32; off > 0; off >>= 1) v += __shfl_down(v, off, 64);
    if ((threadIdx.x & 63) == 0) sb[threadIdx.x >> 6] = v;
    __syncthreads();
    if (threadIdx.x == 0) {
        double t = (double)sb[0] + (double)sb[1] + (double)sb[2] + (double)sb[3];
        atomicAdd(&acc[layer * 8 + 7], t);           // device-scope
        __threadfence();
        int old = atomicAdd(done, 1);
        if (old == NB_IGNORE - 1) {
            // last block: all acc[·] contributions are fenced + visible
            __threadfence();
            double loss = 0.0;
            const int gs[3] = {13, 26, 52};
            for (int l = 0; l < 3; l++) {
                double C = 8.0 * gs[l] * gs[l] * 3.0;
                double q[8];
                #pragma unroll
                for (int k = 0; k < 8; k++)
                    q[k] = __hip_atomic_load(&acc[l*8+k], __ATOMIC_RELAXED,
                                             __HIP_MEMORY_SCOPE_AGENT);
                double cls = (q[0] - q[1]) / (C * 80.0);
                loss += ( (q[2]/(C*2.0))*q[6] + q[3]
                        + (q[4]/C)*(q[5]+q[7]) + cls*q[5] ) / 8.0;
            }
            out[0] = (float)loss;
        }
    }
}

extern "C" void kernel_launch(void* const* d_in, const int* in_sizes, int n_in,
                              void* d_out, int out_size, void* d_ws, size_t ws_size,
                              hipStream_t stream)
{
    const float* o0 = (const float*)d_in[0];
    const float* l0 = (const float*)d_in[1];
    const float* o1 = (const float*)d_in[2];
    const float* l1 = (const float*)d_in[3];
    const float* o2 = (const float*)d_in[4];
    const float* l2 = (const float*)d_in[5];

    double* acc   = (double*)d_ws;
    int*    cnt   = (int*)((char*)d_ws + 192);
    int*    done  = (int*)((char*)d_ws + 288);
    float4* tbox  = (float4*)((char*)d_ws + 512);
    float4* pbox  = (float4*)((char*)d_ws + 1363328);
    float*  noobj = (float*)((char*)d_ws + 2726144);

    hipMemsetAsync(d_ws, 0, 512, stream);   // zero acc + cnt + done
    mega_a<<<2098, BDIM, 0, stream>>>(o0, l0, o1, l1, o2, l2,
                                      acc, cnt, tbox, pbox, noobj);
    ignore_fin<<<NB_IGNORE, BDIM, 0, stream>>>(acc, cnt, tbox, pbox, noobj,
                                               done, (float*)d_out);
}